// Round 15
// baseline (300.773 us; speedup 1.0000x reference)
//
#include <hip/hip_runtime.h>
#include <cstdint>
#include <cstddef>

// ---------------- common ----------------
#define TM 16           // tokens per group
#define IP 136          // padded i-dim (bf16 elems) -> row stride 272 B (17*16B, b128-aligned)
#define SLAB (TM * IP)  // 2176 bf16 per h-slab; 32 slabs * 2B = 139264 B LDS -> 1 block/CU, 16 waves

__device__ __forceinline__ unsigned short f2bf(float f) {
  union { float f; unsigned int u; } c; c.f = f;
  unsigned int u = c.u;
  return (unsigned short)((u + 0x7FFFu + ((u >> 16) & 1u)) >> 16);  // RNE
}
__device__ __forceinline__ float bf2f(unsigned short h) {
  union { unsigned int u; float f; } c; c.u = ((unsigned int)h) << 16; return c.f;
}

// unnormalized 32-pt Walsh-Hadamard; two applications -> /32 folded into beta*scale/32
__device__ __forceinline__ void fht32(float* v) {
  #pragma unroll
  for (int s = 1; s < 32; s <<= 1) {
    #pragma unroll
    for (int a = 0; a < 32; ++a) {
      if ((a & s) == 0) {
        float u0 = v[a], u1 = v[a + s];
        v[a] = u0 + u1;
        v[a + s] = u0 - u1;
      }
    }
  }
}

typedef __attribute__((ext_vector_type(8))) short bf16x8;
typedef __attribute__((ext_vector_type(4))) float f32x4;
typedef __attribute__((ext_vector_type(2))) float f32x2;

// ---------------- pre-pass 1: partial sums of |w| (256 blocks) ----------------
__global__ void kred1(const float* __restrict__ w, double* __restrict__ partials) {
  const int tid = threadIdx.x;                   // 256 thr, 256 blocks
  const int base = blockIdx.x * 2048 + tid;
  double s = 0.0;
  #pragma unroll
  for (int j = 0; j < 8; ++j) s += (double)fabsf(w[base + j * 256]);
  #pragma unroll
  for (int off = 32; off > 0; off >>= 1) s += __shfl_down(s, off, 64);
  __shared__ double sh[4];
  if ((tid & 63) == 0) sh[tid >> 6] = s;
  __syncthreads();
  if (tid == 0) partials[blockIdx.x] = sh[0] + sh[1] + sh[2] + sh[3];
}

// ---------------- pre-pass 2: scale + ternary quantize into fragment order ------
// wqt chunk c (c = blockIdx*256+tid, 65536 chunks of 8 bf16):
//   lane=c&63, ks=(c>>6)&3, nt=(c>>8)&7, h=c>>11, m=lane&15, quad=lane>>4
//   holds wq[h][nt*16+m][ks*32+quad*8 .. +8]  -> phase-2 wave loads fully coalesced.
__global__ void kprep(const float* __restrict__ w, const double* __restrict__ partials,
                      float* __restrict__ scale_out, unsigned short* __restrict__ wqt) {
  const int tid = threadIdx.x;  // 256 thr, 256 blocks
  __shared__ float s_sc;
  if (tid < 64) {               // deterministic redundant re-reduce of 256 partials
    double s = partials[tid] + partials[tid + 64] + partials[tid + 128] + partials[tid + 192];
    #pragma unroll
    for (int off = 32; off > 0; off >>= 1) s += __shfl_down(s, off, 64);
    if (tid == 0) s_sc = (float)(s / 524288.0) + 1e-8f;
  }
  __syncthreads();
  const float sc = s_sc;
  if (blockIdx.x == 0 && tid == 0) scale_out[0] = sc;
  const int cid = blockIdx.x * 256 + tid;
  const int lane = cid & 63, ks = (cid >> 6) & 3, nt = (cid >> 8) & 7, h = cid >> 11;
  const int m = lane & 15, quad = lane >> 4;
  const float* src = w + h * 16384 + (nt * 16 + m) * 128 + ks * 32 + quad * 8;
  bf16x8 vv;
  #pragma unroll
  for (int j = 0; j < 8; ++j) {
    float q = rintf(src[j] / sc);              // round-half-even == np.round
    q = fminf(1.f, fmaxf(-1.f, q));
    vv[j] = (short)f2bf(q);                    // +-1/0 exact in bf16
  }
  *(bf16x8*)(wqt + (size_t)cid * 8) = vv;
}

// ---------------- main fused kernel ----------------
// PERSISTENT: grid 256 (exactly 1 block/CU) x 1024 thr, 2 token-groups per block.
// Phase bodies are byte-for-byte the measured-best R14 (97.5 us). Structural change:
// the two groups run inside one block, and P3 is split {LDS-read -> cheap barrier ->
// fht/mul/store} so group g+1's P1 x-loads issue while group g's y-stores drain
// (the old 2-blocks-per-CU layout forced a full retire+dispatch between them).
// g1's wqt stream re-hits warm L1/L2 (same CU just streamed it).
__global__ __launch_bounds__(1024, 4) void had_main(
    const float* __restrict__ x,
    const unsigned short* __restrict__ wqt,
    const float* __restrict__ alpha,
    const float* __restrict__ beta,
    const float* __restrict__ scale_p,
    float* __restrict__ y) {
  extern __shared__ unsigned short lds[];  // [32 h][TM t][IP i]
  const int tid = threadIdx.x;
  const int t  = tid >> 6;          // 0..15 : token within group
  const int ih = (tid & 63) << 1;   // 0..126 even : i-pair base

  const int wave = tid >> 6;     // 0..15
  const int lane = tid & 63;
  const unsigned short* wh0 = wqt + (size_t)(wave)      * 16384 + (size_t)lane * 8;
  const unsigned short* wh1 = wqt + (size_t)(wave + 16) * 16384 + (size_t)lane * 8;
  bf16x8 b0[4], b1[4], b2[4];

  #pragma unroll
  for (int g = 0; g < 2; ++g) {
    const long tok0 = (long)blockIdx.x * (2 * TM) + (long)g * TM;

    // ---- Phase 1 ----  (issues x loads right after prev group's y stores)
    {
      const float* xrow = x + (size_t)(tok0 + t) * 4096 + ih;
      float va[32], vb[32];
      #pragma unroll
      for (int gg = 0; gg < 32; ++gg) {
        f32x2 v = *(const f32x2*)(xrow + (size_t)gg * 128);
        va[gg] = v[0]; vb[gg] = v[1];
      }
      #pragma unroll
      for (int gg = 0; gg < 32; ++gg) {
        f32x2 a = *(const f32x2*)(alpha + gg * 128 + ih);
        va[gg] *= a[0]; vb[gg] *= a[1];
      }
      fht32(va);
      fht32(vb);
      #pragma unroll
      for (int h = 0; h < 32; ++h) {
        unsigned int pk = (unsigned int)f2bf(va[h]) | ((unsigned int)f2bf(vb[h]) << 16);
        *(unsigned int*)(lds + (h * TM + t) * IP + ih) = pk;
      }
    }
    // pre-barrier weight prefetch (va/vb dead here): L2 latency drains under barrier
    #pragma unroll
    for (int ks = 0; ks < 4; ++ks) b0[ks] = *(const bf16x8*)(wh0 + (size_t)ks * 512);
    #pragma unroll
    for (int ks = 0; ks < 4; ++ks) b1[ks] = *(const bf16x8*)(wh0 + (size_t)(4 + ks) * 512);
    __syncthreads();

    // ---- Phase 2 ----
    {
      const int m = lane & 15;       // B-col (o) / C-col (o) / A-row (t)
      const int quad = lane >> 4;    // k-chunk; C-row group
      unsigned short* slab0 = lds + (wave)      * SLAB;
      unsigned short* slab1 = lds + (wave + 16) * SLAB;
      // A fragments for both owned h (reads complete before any same-wave writes)
      bf16x8 af0[4], af1[4];
      #pragma unroll
      for (int ks = 0; ks < 4; ++ks) {
        af0[ks] = *(const bf16x8*)(slab0 + m * IP + ks * 32 + quad * 8);
        af1[ks] = *(const bf16x8*)(slab1 + m * IP + ks * 32 + quad * 8);
      }
      // depth-2 rolling B prefetch over flattened 16 steps: step s -> h-half s>>3, nt = s&7
      #pragma unroll
      for (int s = 0; s < 16; ++s) {
        const int nt = s & 7;
        if (s < 14) {
          const int s2 = s + 2;
          const unsigned short* wsrc =
              (s2 < 8 ? wh0 : wh1) + (size_t)((s2 & 7) * 4) * 512;
          #pragma unroll
          for (int ks = 0; ks < 4; ++ks) b2[ks] = *(const bf16x8*)(wsrc + (size_t)ks * 512);
        }
        f32x4 acc = {0.f, 0.f, 0.f, 0.f};
        const bf16x8* af = (s < 8) ? af0 : af1;  // static after unroll
        #pragma unroll
        for (int ks = 0; ks < 4; ++ks)
          acc = __builtin_amdgcn_mfma_f32_16x16x32_bf16(af[ks], b0[ks], acc, 0, 0, 0);
        // C: col = m (o), row = quad*4+r (t). All 16 rows are real tokens.
        unsigned short* slab = (s < 8) ? slab0 : slab1;
        #pragma unroll
        for (int r = 0; r < 4; ++r)
          slab[(quad * 4 + r) * IP + nt * 16 + m] = f2bf(acc[r]);
        #pragma unroll
        for (int ks = 0; ks < 4; ++ks) { b0[ks] = b1[ks]; b1[ks] = b2[ks]; }
      }
    }
    __syncthreads();

    // ---- Phase 3 ----
    {
      const float sc32 = scale_p[0] * (1.0f / 32.0f);
      float v0[32], v1[32];
      #pragma unroll
      for (int h = 0; h < 32; ++h) {
        unsigned int pk = *(const unsigned int*)(lds + (h * TM + t) * IP + ih);
        v0[h] = bf2f((unsigned short)(pk & 0xFFFFu));
        v1[h] = bf2f((unsigned short)(pk >> 16));
      }
      // all LDS reads done -> LDS free for next group's P1. Cheap barrier:
      // no global ops outstanding at this point (stores come after).
      __syncthreads();
      fht32(v0);
      fht32(v1);
      float* yrow = y + (size_t)(tok0 + t) * 4096 + ih;
      #pragma unroll
      for (int gg = 0; gg < 32; ++gg) {
        f32x2 b = *(const f32x2*)(beta + gg * 128 + ih);
        const float c0 = b[0] * sc32;   // keep beta*sc32 first (same order as baseline)
        const float c1 = b[1] * sc32;
        f32x2 o; o[0] = v0[gg] * c0; o[1] = v1[gg] * c1;
        *(f32x2*)(yrow + (size_t)gg * 128) = o;
      }
    }
    // next iteration's P1 x-loads issue here while this group's y-stores drain
  }
}

// ---------------- launcher ----------------
extern "C" void kernel_launch(void* const* d_in, const int* in_sizes, int n_in,
                              void* d_out, int out_size, void* d_ws, size_t ws_size,
                              hipStream_t stream) {
  (void)in_sizes; (void)n_in; (void)out_size; (void)ws_size;
  const float* x     = (const float*)d_in[0];  // fp32 [4,2048,4096]
  const float* w     = (const float*)d_in[1];  // fp32 [32,128,128]
  const float* alpha = (const float*)d_in[2];  // fp32 [32,128]
  const float* beta  = (const float*)d_in[3];  // fp32 [32,128]
  float* y = (float*)d_out;

  char* ws = (char*)d_ws;
  unsigned short* wqt = (unsigned short*)(ws);   // 1 MB ternary bf16, fragment order
  float* scale     = (float*)(ws + 1048576);     // 4 B
  double* partials = (double*)(ws + 1048584);    // 256 doubles (8-aligned)

  (void)hipFuncSetAttribute(reinterpret_cast<const void*>(had_main),
                            hipFuncAttributeMaxDynamicSharedMemorySize, 139264);

  hipLaunchKernelGGL(kred1,    dim3(256), dim3(256),  0,      stream, w, partials);
  hipLaunchKernelGGL(kprep,    dim3(256), dim3(256),  0,      stream, w, partials, scale, wqt);
  hipLaunchKernelGGL(had_main, dim3(256), dim3(1024), 139264, stream, x, wqt, alpha, beta, scale, y);
}

// Round 16
// 265.533 us; speedup vs baseline: 1.1327x; 1.1327x over previous
//
#include <hip/hip_runtime.h>
#include <cstdint>
#include <cstddef>

// ---------------- common ----------------
#define TM 16           // tokens per block
#define IP 136          // padded i-dim (bf16 elems) -> row stride 272 B (17*16B, b128-aligned)
#define SLAB (TM * IP)  // 2176 bf16 per h-slab; 32 slabs * 2B = 139264 B LDS -> 1 block/CU, 16 waves

__device__ __forceinline__ unsigned short f2bf(float f) {
  union { float f; unsigned int u; } c; c.f = f;
  unsigned int u = c.u;
  return (unsigned short)((u + 0x7FFFu + ((u >> 16) & 1u)) >> 16);  // RNE
}
__device__ __forceinline__ float bf2f(unsigned short h) {
  union { unsigned int u; float f; } c; c.u = ((unsigned int)h) << 16; return c.f;
}

// unnormalized 32-pt Walsh-Hadamard; two applications -> /32 folded into beta*scale/32
__device__ __forceinline__ void fht32(float* v) {
  #pragma unroll
  for (int s = 1; s < 32; s <<= 1) {
    #pragma unroll
    for (int a = 0; a < 32; ++a) {
      if ((a & s) == 0) {
        float u0 = v[a], u1 = v[a + s];
        v[a] = u0 + u1;
        v[a + s] = u0 - u1;
      }
    }
  }
}

typedef __attribute__((ext_vector_type(8))) short bf16x8;
typedef __attribute__((ext_vector_type(4))) float f32x4;
typedef __attribute__((ext_vector_type(2))) float f32x2;

// ---------------- pre-pass 1: partial sums of |w| (256 blocks) ----------------
__global__ void kred1(const float* __restrict__ w, double* __restrict__ partials) {
  const int tid = threadIdx.x;                   // 256 thr, 256 blocks
  const int base = blockIdx.x * 2048 + tid;
  double s = 0.0;
  #pragma unroll
  for (int j = 0; j < 8; ++j) s += (double)fabsf(w[base + j * 256]);
  #pragma unroll
  for (int off = 32; off > 0; off >>= 1) s += __shfl_down(s, off, 64);
  __shared__ double sh[4];
  if ((tid & 63) == 0) sh[tid >> 6] = s;
  __syncthreads();
  if (tid == 0) partials[blockIdx.x] = sh[0] + sh[1] + sh[2] + sh[3];
}

// ---------------- pre-pass 2: scale + ternary quantize into fragment order ------
// wqt chunk c (c = blockIdx*256+tid, 65536 chunks of 8 bf16):
//   lane=c&63, ks=(c>>6)&3, nt=(c>>8)&7, h=c>>11, m=lane&15, quad=lane>>4
//   holds wq[h][nt*16+m][ks*32+quad*8 .. +8]  -> phase-2 wave loads fully coalesced.
__global__ void kprep(const float* __restrict__ w, const double* __restrict__ partials,
                      float* __restrict__ scale_out, unsigned short* __restrict__ wqt) {
  const int tid = threadIdx.x;  // 256 thr, 256 blocks
  __shared__ float s_sc;
  if (tid < 64) {               // deterministic redundant re-reduce of 256 partials
    double s = partials[tid] + partials[tid + 64] + partials[tid + 128] + partials[tid + 192];
    #pragma unroll
    for (int off = 32; off > 0; off >>= 1) s += __shfl_down(s, off, 64);
    if (tid == 0) s_sc = (float)(s / 524288.0) + 1e-8f;
  }
  __syncthreads();
  const float sc = s_sc;
  if (blockIdx.x == 0 && tid == 0) scale_out[0] = sc;
  const int cid = blockIdx.x * 256 + tid;
  const int lane = cid & 63, ks = (cid >> 6) & 3, nt = (cid >> 8) & 7, h = cid >> 11;
  const int m = lane & 15, quad = lane >> 4;
  const float* src = w + h * 16384 + (nt * 16 + m) * 128 + ks * 32 + quad * 8;
  bf16x8 vv;
  #pragma unroll
  for (int j = 0; j < 8; ++j) {
    float q = rintf(src[j] / sc);              // round-half-even == np.round
    q = fminf(1.f, fmaxf(-1.f, q));
    vv[j] = (short)f2bf(q);                    // +-1/0 exact in bf16
  }
  *(bf16x8*)(wqt + (size_t)cid * 8) = vv;
}

// ---------------- main fused kernel ----------------
// grid 512 blocks (16 tokens) x 1024 thr (16 waves), 139264 B dynamic LDS -> 1 block/CU.
// MEASURED-BEST structure (R14: 97.5 us). Paired-dwordx2 P1, flattened 16-step P2
// with depth-2 B prefetch, packed single-pass P3, and b0/b1 weight tiles issued
// BEFORE the P1->P2 barrier (L2 latency drains under the barrier).
// DO NOT: split P3 around a barrier (R15: v0/v1 live across barrier -> 76 B/thread
// spill, 143.6 us) or serialize P1/P3 into two passes (R13: MLP loss, 131.4 us).
// The ~12 B/thread residual spill here is cheaper than any structure that avoids it.
__global__ __launch_bounds__(1024, 4) void had_main(
    const float* __restrict__ x,
    const unsigned short* __restrict__ wqt,
    const float* __restrict__ alpha,
    const float* __restrict__ beta,
    const float* __restrict__ scale_p,
    float* __restrict__ y) {
  extern __shared__ unsigned short lds[];  // [32 h][TM t][IP i]
  const int tid = threadIdx.x;
  const long tok0 = (long)blockIdx.x * TM;
  const int t  = tid >> 6;          // 0..15 : token within block
  const int ih = (tid & 63) << 1;   // 0..126 even : i-pair base

  const int wave = tid >> 6;     // 0..15
  const int lane = tid & 63;
  const unsigned short* wh0 = wqt + (size_t)(wave)      * 16384 + (size_t)lane * 8;
  const unsigned short* wh1 = wqt + (size_t)(wave + 16) * 16384 + (size_t)lane * 8;
  bf16x8 b0[4], b1[4], b2[4];

  // ---- Phase 1 ----
  {
    const float* xrow = x + (size_t)(tok0 + t) * 4096 + ih;
    float va[32], vb[32];
    #pragma unroll
    for (int g = 0; g < 32; ++g) {
      f32x2 v = *(const f32x2*)(xrow + (size_t)g * 128);
      va[g] = v[0]; vb[g] = v[1];
    }
    #pragma unroll
    for (int g = 0; g < 32; ++g) {
      f32x2 a = *(const f32x2*)(alpha + g * 128 + ih);
      va[g] *= a[0]; vb[g] *= a[1];
    }
    fht32(va);
    fht32(vb);
    #pragma unroll
    for (int h = 0; h < 32; ++h) {
      unsigned int pk = (unsigned int)f2bf(va[h]) | ((unsigned int)f2bf(vb[h]) << 16);
      *(unsigned int*)(lds + (h * TM + t) * IP + ih) = pk;
    }
  }
  // pre-barrier weight prefetch: va/vb are dead here, pressure is low; the two
  // B tiles' L2 latency overlaps the barrier drain.
  #pragma unroll
  for (int ks = 0; ks < 4; ++ks) b0[ks] = *(const bf16x8*)(wh0 + (size_t)ks * 512);
  #pragma unroll
  for (int ks = 0; ks < 4; ++ks) b1[ks] = *(const bf16x8*)(wh0 + (size_t)(4 + ks) * 512);
  __syncthreads();

  // ---- Phase 2 ----
  {
    const int m = lane & 15;       // B-col (o) / C-col (o) / A-row (t)
    const int quad = lane >> 4;    // k-chunk; C-row group
    unsigned short* slab0 = lds + (wave)      * SLAB;
    unsigned short* slab1 = lds + (wave + 16) * SLAB;
    // A fragments for both owned h (reads complete before any same-wave writes)
    bf16x8 af0[4], af1[4];
    #pragma unroll
    for (int ks = 0; ks < 4; ++ks) {
      af0[ks] = *(const bf16x8*)(slab0 + m * IP + ks * 32 + quad * 8);
      af1[ks] = *(const bf16x8*)(slab1 + m * IP + ks * 32 + quad * 8);
    }
    // depth-2 rolling B prefetch over flattened 16 steps: step s -> h-half s>>3, nt = s&7
    #pragma unroll
    for (int s = 0; s < 16; ++s) {
      const int nt = s & 7;
      if (s < 14) {
        const int s2 = s + 2;
        const unsigned short* wsrc =
            (s2 < 8 ? wh0 : wh1) + (size_t)((s2 & 7) * 4) * 512;
        #pragma unroll
        for (int ks = 0; ks < 4; ++ks) b2[ks] = *(const bf16x8*)(wsrc + (size_t)ks * 512);
      }
      f32x4 acc = {0.f, 0.f, 0.f, 0.f};
      const bf16x8* af = (s < 8) ? af0 : af1;  // static after unroll
      #pragma unroll
      for (int ks = 0; ks < 4; ++ks)
        acc = __builtin_amdgcn_mfma_f32_16x16x32_bf16(af[ks], b0[ks], acc, 0, 0, 0);
      // C: col = m (o), row = quad*4+r (t). All 16 rows are real tokens.
      unsigned short* slab = (s < 8) ? slab0 : slab1;
      #pragma unroll
      for (int r = 0; r < 4; ++r)
        slab[(quad * 4 + r) * IP + nt * 16 + m] = f2bf(acc[r]);
      #pragma unroll
      for (int ks = 0; ks < 4; ++ks) { b0[ks] = b1[ks]; b1[ks] = b2[ks]; }
    }
  }
  __syncthreads();

  // ---- Phase 3 ----
  {
    const float sc32 = scale_p[0] * (1.0f / 32.0f);
    float v0[32], v1[32];
    #pragma unroll
    for (int h = 0; h < 32; ++h) {
      unsigned int pk = *(const unsigned int*)(lds + (h * TM + t) * IP + ih);
      v0[h] = bf2f((unsigned short)(pk & 0xFFFFu));
      v1[h] = bf2f((unsigned short)(pk >> 16));
    }
    fht32(v0);
    fht32(v1);
    float* yrow = y + (size_t)(tok0 + t) * 4096 + ih;
    #pragma unroll
    for (int g = 0; g < 32; ++g) {
      f32x2 b = *(const f32x2*)(beta + g * 128 + ih);
      const float c0 = b[0] * sc32;   // keep beta*sc32 first (same order as baseline)
      const float c1 = b[1] * sc32;
      f32x2 o; o[0] = v0[g] * c0; o[1] = v1[g] * c1;
      *(f32x2*)(yrow + (size_t)g * 128) = o;
    }
  }
}

// ---------------- launcher ----------------
extern "C" void kernel_launch(void* const* d_in, const int* in_sizes, int n_in,
                              void* d_out, int out_size, void* d_ws, size_t ws_size,
                              hipStream_t stream) {
  (void)in_sizes; (void)n_in; (void)out_size; (void)ws_size;
  const float* x     = (const float*)d_in[0];  // fp32 [4,2048,4096]
  const float* w     = (const float*)d_in[1];  // fp32 [32,128,128]
  const float* alpha = (const float*)d_in[2];  // fp32 [32,128]
  const float* beta  = (const float*)d_in[3];  // fp32 [32,128]
  float* y = (float*)d_out;

  char* ws = (char*)d_ws;
  unsigned short* wqt = (unsigned short*)(ws);   // 1 MB ternary bf16, fragment order
  float* scale     = (float*)(ws + 1048576);     // 4 B
  double* partials = (double*)(ws + 1048584);    // 256 doubles (8-aligned)

  (void)hipFuncSetAttribute(reinterpret_cast<const void*>(had_main),
                            hipFuncAttributeMaxDynamicSharedMemorySize, 139264);

  hipLaunchKernelGGL(kred1,    dim3(256), dim3(256),  0,      stream, w, partials);
  hipLaunchKernelGGL(kprep,    dim3(256), dim3(256),  0,      stream, w, partials, scale, wqt);
  hipLaunchKernelGGL(had_main, dim3(512), dim3(1024), 139264, stream, x, wqt, alpha, beta, scale, y);
}

// Round 17
// 265.118 us; speedup vs baseline: 1.1345x; 1.0016x over previous
//
#include <hip/hip_runtime.h>
#include <cstdint>
#include <cstddef>

// ---------------- common ----------------
#define TM 16           // tokens per block
#define IP 136          // padded i-dim (bf16 elems) -> row stride 272 B (17*16B, b128-aligned)
#define SLAB (TM * IP)  // 2176 bf16 per h-slab; 32 slabs * 2B = 139264 B LDS -> 1 block/CU, 16 waves

__device__ __forceinline__ unsigned short f2bf(float f) {
  union { float f; unsigned int u; } c; c.f = f;
  unsigned int u = c.u;
  return (unsigned short)((u + 0x7FFFu + ((u >> 16) & 1u)) >> 16);  // RNE
}
__device__ __forceinline__ float bf2f(unsigned short h) {
  union { unsigned int u; float f; } c; c.u = ((unsigned int)h) << 16; return c.f;
}

// unnormalized 32-pt Walsh-Hadamard; two applications -> /32 folded into beta*scale/32
__device__ __forceinline__ void fht32(float* v) {
  #pragma unroll
  for (int s = 1; s < 32; s <<= 1) {
    #pragma unroll
    for (int a = 0; a < 32; ++a) {
      if ((a & s) == 0) {
        float u0 = v[a], u1 = v[a + s];
        v[a] = u0 + u1;
        v[a + s] = u0 - u1;
      }
    }
  }
}

typedef __attribute__((ext_vector_type(8))) short bf16x8;
typedef __attribute__((ext_vector_type(4))) float f32x4;
typedef __attribute__((ext_vector_type(2))) float f32x2;

// ---------------- pre-pass 1: partial sums of |w| (256 blocks) ----------------
__global__ void kred1(const float* __restrict__ w, double* __restrict__ partials) {
  const int tid = threadIdx.x;                   // 256 thr, 256 blocks
  const int base = blockIdx.x * 2048 + tid;
  double s = 0.0;
  #pragma unroll
  for (int j = 0; j < 8; ++j) s += (double)fabsf(w[base + j * 256]);
  #pragma unroll
  for (int off = 32; off > 0; off >>= 1) s += __shfl_down(s, off, 64);
  __shared__ double sh[4];
  if ((tid & 63) == 0) sh[tid >> 6] = s;
  __syncthreads();
  if (tid == 0) partials[blockIdx.x] = sh[0] + sh[1] + sh[2] + sh[3];
}

// ---------------- pre-pass 2: scale + ternary quantize into fragment order ------
// wqt chunk c (c = blockIdx*256+tid, 65536 chunks of 8 bf16):
//   lane=c&63, ks=(c>>6)&3, nt=(c>>8)&7, h=c>>11, m=lane&15, quad=lane>>4
//   holds wq[h][nt*16+m][ks*32+quad*8 .. +8]  -> phase-2 wave loads fully coalesced.
__global__ void kprep(const float* __restrict__ w, const double* __restrict__ partials,
                      float* __restrict__ scale_out, unsigned short* __restrict__ wqt) {
  const int tid = threadIdx.x;  // 256 thr, 256 blocks
  __shared__ float s_sc;
  if (tid < 64) {               // deterministic redundant re-reduce of 256 partials
    double s = partials[tid] + partials[tid + 64] + partials[tid + 128] + partials[tid + 192];
    #pragma unroll
    for (int off = 32; off > 0; off >>= 1) s += __shfl_down(s, off, 64);
    if (tid == 0) s_sc = (float)(s / 524288.0) + 1e-8f;
  }
  __syncthreads();
  const float sc = s_sc;
  if (blockIdx.x == 0 && tid == 0) scale_out[0] = sc;
  const int cid = blockIdx.x * 256 + tid;
  const int lane = cid & 63, ks = (cid >> 6) & 3, nt = (cid >> 8) & 7, h = cid >> 11;
  const int m = lane & 15, quad = lane >> 4;
  const float* src = w + h * 16384 + (nt * 16 + m) * 128 + ks * 32 + quad * 8;
  bf16x8 vv;
  #pragma unroll
  for (int j = 0; j < 8; ++j) {
    float q = rintf(src[j] / sc);              // round-half-even == np.round
    q = fminf(1.f, fmaxf(-1.f, q));
    vv[j] = (short)f2bf(q);                    // +-1/0 exact in bf16
  }
  *(bf16x8*)(wqt + (size_t)cid * 8) = vv;
}

// ---------------- main fused kernel ----------------
// grid 512 blocks (16 tokens) x 1024 thr (16 waves), 139264 B dynamic LDS -> 1 block/CU.
// MEASURED-BEST structure (R14/R16: 97.5-98 us, reproduced). Single change this
// round: pre-barrier weight prefetch deepened 2->3 tiles (b0,b1,b2; 48 regs live
// at the barrier where va/vb are dead — still under the 64-VGPR cap), so P2's
// first prefetch L2 latency drains under the barrier; rolling prefetch starts at
// s2=3. scale_p scalar load hoisted to entry.
// DO NOT: split P3 around a barrier (R15: 76 B/thread spill, 143.6 us) or
// serialize P1/P3 into two passes (R13: MLP loss, 131.4 us).
__global__ __launch_bounds__(1024, 4) void had_main(
    const float* __restrict__ x,
    const unsigned short* __restrict__ wqt,
    const float* __restrict__ alpha,
    const float* __restrict__ beta,
    const float* __restrict__ scale_p,
    float* __restrict__ y) {
  extern __shared__ unsigned short lds[];  // [32 h][TM t][IP i]
  const int tid = threadIdx.x;
  const long tok0 = (long)blockIdx.x * TM;
  const int t  = tid >> 6;          // 0..15 : token within block
  const int ih = (tid & 63) << 1;   // 0..126 even : i-pair base

  const int wave = tid >> 6;     // 0..15
  const int lane = tid & 63;
  const unsigned short* wh0 = wqt + (size_t)(wave)      * 16384 + (size_t)lane * 8;
  const unsigned short* wh1 = wqt + (size_t)(wave + 16) * 16384 + (size_t)lane * 8;
  const float sc32 = scale_p[0] * (1.0f / 32.0f);   // s_load latency hides under P1
  bf16x8 b0[4], b1[4], b2[4];

  // ---- Phase 1 ----
  {
    const float* xrow = x + (size_t)(tok0 + t) * 4096 + ih;
    float va[32], vb[32];
    #pragma unroll
    for (int g = 0; g < 32; ++g) {
      f32x2 v = *(const f32x2*)(xrow + (size_t)g * 128);
      va[g] = v[0]; vb[g] = v[1];
    }
    #pragma unroll
    for (int g = 0; g < 32; ++g) {
      f32x2 a = *(const f32x2*)(alpha + g * 128 + ih);
      va[g] *= a[0]; vb[g] *= a[1];
    }
    fht32(va);
    fht32(vb);
    #pragma unroll
    for (int h = 0; h < 32; ++h) {
      unsigned int pk = (unsigned int)f2bf(va[h]) | ((unsigned int)f2bf(vb[h]) << 16);
      *(unsigned int*)(lds + (h * TM + t) * IP + ih) = pk;
    }
  }
  // pre-barrier weight prefetch (3 tiles): va/vb are dead here, pressure is low;
  // all three tiles' L2 latency overlaps the barrier drain.
  #pragma unroll
  for (int ks = 0; ks < 4; ++ks) b0[ks] = *(const bf16x8*)(wh0 + (size_t)ks * 512);
  #pragma unroll
  for (int ks = 0; ks < 4; ++ks) b1[ks] = *(const bf16x8*)(wh0 + (size_t)(4 + ks) * 512);
  #pragma unroll
  for (int ks = 0; ks < 4; ++ks) b2[ks] = *(const bf16x8*)(wh0 + (size_t)(8 + ks) * 512);
  __syncthreads();

  // ---- Phase 2 ----
  {
    const int m = lane & 15;       // B-col (o) / C-col (o) / A-row (t)
    const int quad = lane >> 4;    // k-chunk; C-row group
    unsigned short* slab0 = lds + (wave)      * SLAB;
    unsigned short* slab1 = lds + (wave + 16) * SLAB;
    // A fragments for both owned h (reads complete before any same-wave writes)
    bf16x8 af0[4], af1[4];
    #pragma unroll
    for (int ks = 0; ks < 4; ++ks) {
      af0[ks] = *(const bf16x8*)(slab0 + m * IP + ks * 32 + quad * 8);
      af1[ks] = *(const bf16x8*)(slab1 + m * IP + ks * 32 + quad * 8);
    }
    // depth-2 rolling B prefetch over flattened 16 steps: step s -> h-half s>>3, nt = s&7.
    // Tiles 0..2 were pre-loaded before the barrier, so the loop prefetches s+3.
    #pragma unroll
    for (int s = 0; s < 16; ++s) {
      const int nt = s & 7;
      f32x4 acc = {0.f, 0.f, 0.f, 0.f};
      const bf16x8* af = (s < 8) ? af0 : af1;  // static after unroll
      #pragma unroll
      for (int ks = 0; ks < 4; ++ks)
        acc = __builtin_amdgcn_mfma_f32_16x16x32_bf16(af[ks], b0[ks], acc, 0, 0, 0);
      // C: col = m (o), row = quad*4+r (t). All 16 rows are real tokens.
      unsigned short* slab = (s < 8) ? slab0 : slab1;
      #pragma unroll
      for (int r = 0; r < 4; ++r)
        slab[(quad * 4 + r) * IP + nt * 16 + m] = f2bf(acc[r]);
      #pragma unroll
      for (int ks = 0; ks < 4; ++ks) { b0[ks] = b1[ks]; b1[ks] = b2[ks]; }
      if (s < 13) {
        const int s3 = s + 3;
        const unsigned short* wsrc =
            (s3 < 8 ? wh0 : wh1) + (size_t)((s3 & 7) * 4) * 512;
        #pragma unroll
        for (int ks = 0; ks < 4; ++ks) b2[ks] = *(const bf16x8*)(wsrc + (size_t)ks * 512);
      }
    }
  }
  __syncthreads();

  // ---- Phase 3 ----
  {
    float v0[32], v1[32];
    #pragma unroll
    for (int h = 0; h < 32; ++h) {
      unsigned int pk = *(const unsigned int*)(lds + (h * TM + t) * IP + ih);
      v0[h] = bf2f((unsigned short)(pk & 0xFFFFu));
      v1[h] = bf2f((unsigned short)(pk >> 16));
    }
    fht32(v0);
    fht32(v1);
    float* yrow = y + (size_t)(tok0 + t) * 4096 + ih;
    #pragma unroll
    for (int g = 0; g < 32; ++g) {
      f32x2 b = *(const f32x2*)(beta + g * 128 + ih);
      const float c0 = b[0] * sc32;   // keep beta*sc32 first (same order as baseline)
      const float c1 = b[1] * sc32;
      f32x2 o; o[0] = v0[g] * c0; o[1] = v1[g] * c1;
      *(f32x2*)(yrow + (size_t)g * 128) = o;
    }
  }
}

// ---------------- launcher ----------------
extern "C" void kernel_launch(void* const* d_in, const int* in_sizes, int n_in,
                              void* d_out, int out_size, void* d_ws, size_t ws_size,
                              hipStream_t stream) {
  (void)in_sizes; (void)n_in; (void)out_size; (void)ws_size;
  const float* x     = (const float*)d_in[0];  // fp32 [4,2048,4096]
  const float* w     = (const float*)d_in[1];  // fp32 [32,128,128]
  const float* alpha = (const float*)d_in[2];  // fp32 [32,128]
  const float* beta  = (const float*)d_in[3];  // fp32 [32,128]
  float* y = (float*)d_out;

  char* ws = (char*)d_ws;
  unsigned short* wqt = (unsigned short*)(ws);   // 1 MB ternary bf16, fragment order
  float* scale     = (float*)(ws + 1048576);     // 4 B
  double* partials = (double*)(ws + 1048584);    // 256 doubles (8-aligned)

  (void)hipFuncSetAttribute(reinterpret_cast<const void*>(had_main),
                            hipFuncAttributeMaxDynamicSharedMemorySize, 139264);

  hipLaunchKernelGGL(kred1,    dim3(256), dim3(256),  0,      stream, w, partials);
  hipLaunchKernelGGL(kprep,    dim3(256), dim3(256),  0,      stream, w, partials, scale, wqt);
  hipLaunchKernelGGL(had_main, dim3(512), dim3(1024), 139264, stream, x, wqt, alpha, beta, scale, y);
}